// Round 1
// baseline (12.801 us; speedup 1.0000x reference)
//
#include <hip/hip_runtime.h>

#define N 2048
#define B 8

__global__ void InterfaceBoundaryLoss_80650895884611_kernel(
    const float* __restrict__ uin,
    const float* __restrict__ uout,
    const int*   __restrict__ xi,
    const int*   __restrict__ yi,
    const float* __restrict__ nxs,
    const float* __restrict__ nys,
    float* __restrict__ out,
    int M, float scale)
{
    const float invDX = (float)(N - 1);   // 2047: DX = DY = 1/(N-1)
    const int total = B * M;
    float acc = 0.0f;

    for (int idx = blockIdx.x * blockDim.x + threadIdx.x; idx < total;
         idx += gridDim.x * blockDim.x) {
        int b = idx / M;
        int k = idx - b * M;

        int   x  = xi[k];
        int   y  = yi[k];
        float nx = nxs[k];
        float ny = nys[k];

        const float* pin  = uin  + (size_t)b * N * N + (size_t)x * N + y;
        const float* pout = uout + (size_t)b * N * N + (size_t)x * N + y;

        float c_in = pin[0];
        float l_in = pin[-N];
        float r_in = pin[N];
        float d_in = pin[-1];
        float a_in = pin[1];

        float c_o  = pout[0];
        float l_o  = pout[-N];
        float r_o  = pout[N];
        float d_o  = pout[-1];
        float a_o  = pout[1];

        // reference: gx_in = nx>0 ? (c-l)/DX : (r-c)/DX ; gx_out mirrored
        float gx_in = (nx > 0.0f) ? (c_in - l_in) : (r_in - c_in);
        float gx_o  = (nx > 0.0f) ? (r_o  - c_o ) : (c_o  - l_o );
        float gy_in = (ny > 0.0f) ? (c_in - d_in) : (a_in - c_in);
        float gy_o  = (ny > 0.0f) ? (a_o  - c_o ) : (c_o  - d_o );

        // nd = (gx*nx + gy*ny) / DX, with 1/DX factored out
        float nd_in = (gx_in * nx + gy_in * ny) * invDX;
        float nd_o  = (gx_o  * nx + gy_o  * ny) * invDX;

        float d1 = c_in - c_o;
        float d2 = nd_in - 80.0f * nd_o;   // E_IN=1, E_OUT=80
        acc += d1 * d1 + d2 * d2;
    }

    // wave-64 butterfly reduce
    #pragma unroll
    for (int off = 32; off > 0; off >>= 1)
        acc += __shfl_down(acc, off, 64);

    __shared__ float ws[4];               // 256 threads = 4 waves
    int lane = threadIdx.x & 63;
    int wid  = threadIdx.x >> 6;
    if (lane == 0) ws[wid] = acc;
    __syncthreads();

    if (threadIdx.x == 0) {
        float s = ws[0] + ws[1] + ws[2] + ws[3];
        atomicAdd(out, s * scale);
    }
}

extern "C" void kernel_launch(void* const* d_in, const int* in_sizes, int n_in,
                              void* d_out, int out_size, void* d_ws, size_t ws_size,
                              hipStream_t stream) {
    const float* uin  = (const float*)d_in[0];
    const float* uout = (const float*)d_in[1];
    const int*   xi   = (const int*)d_in[2];
    const int*   yi   = (const int*)d_in[3];
    const float* nxs  = (const float*)d_in[4];
    const float* nys  = (const float*)d_in[5];
    float* out = (float*)d_out;

    const int M = in_sizes[2];
    const float scale = 1.0f / (float)(B * M);

    // d_out is poisoned once and never re-zeroed between replays
    hipMemsetAsync(d_out, 0, sizeof(float), stream);

    const int total = B * M;
    const int block = 256;
    int grid = (total + block - 1) / block;
    if (grid > 2048) grid = 2048;

    InterfaceBoundaryLoss_80650895884611_kernel<<<grid, block, 0, stream>>>(
        uin, uout, xi, yi, nxs, nys, out, M, scale);
}